// Round 1
// baseline (237.420 us; speedup 1.0000x reference)
//
#include <hip/hip_runtime.h>

typedef __bf16 bf16x8 __attribute__((ext_vector_type(8)));
typedef float  floatx16 __attribute__((ext_vector_type(16)));

#define HW   56
#define NPIX 3136
#define CIN  128
#define COUT 256

// W2 layout: [cc(4)][tap(9)][cg(4)][oc(256)][j(8)], bf16. 576 KB of d_ws.
__global__ __launch_bounds__(256) void wt_transform_kernel(
        const float* __restrict__ Kw, __bf16* __restrict__ W2) {
    int idx = blockIdx.x * 256 + threadIdx.x;     // coalesced write
    int j     = idx & 7;
    int oc    = (idx >> 3) & 255;
    int cg    = (idx >> 11) & 3;
    int tapcc = idx >> 13;                        // cc*9 + tap
    int tap   = tapcc % 9;
    int cc    = tapcc / 9;
    int c = cc * 32 + cg * 8 + j;
    W2[idx] = (__bf16)Kw[oc * 1152 + c * 9 + tap];
}

// Xs: [buf(2)][row(4)][wp(66)][slot(40)] bf16; slots 0..31 = ci (cg*8+j), 32..39 pad.
// Stride 40 elems = 80 B: bank-base advances 20 banks/wp -> conflict-free b128.
__device__ __forceinline__ int xs_idx(int row, int wp, int cg) {
    return row * 2640 + wp * 40 + cg * 8;
}

// Block: 256 thr = 4 waves. Block tile: 128 oc x 128 pos (2 out-rows x 64 wpad).
// Wave: 64 oc x 64 pos (one out-row) -> 2mi x 2nj of 32x32x16, acc = 64 AGPR.
// R3: T14 async-STAGE split + LDS double-buffer. The R2 bottleneck was exposed
// staging latency: vmcnt(0)+barrier every cc put ~1-2k cycles of HBM latency on
// every wave's critical path (all pipes <30%). Now: issue next-cc global loads
// into registers BEFORE the 72-MFMA compute phase (~2300 cyc covers HBM lat),
// convert+ds_write into the other buffer after compute, 1 barrier/cc (was 2).
__global__ __launch_bounds__(256, 3) void conv_kernel(
        const float* __restrict__ x, const __bf16* __restrict__ W2,
        const float* __restrict__ bias, float* __restrict__ out) {
    __shared__ __align__(16) __bf16 Xs[2][4 * 2640];   // 42.2 KB -> still 3 blk/CU

    const int t    = threadIdx.x;
    const int nb   = blockIdx.x / 28;
    const int ht   = blockIdx.x % 28;
    const int h0   = ht * 2;
    const int ocb  = blockIdx.y * 128;

    const int wid  = t >> 6;
    const int lane = t & 63;
    const int half = lane >> 5;
    const int l31  = lane & 31;

    const int oc_base = ocb + (wid & 1) * 64;   // wave's 64-oc slice
    const int prow    = wid >> 1;               // wave's output row (0/1)

    floatx16 acc[2][2];
    #pragma unroll
    for (int mi = 0; mi < 2; ++mi)
        #pragma unroll
        for (int nj = 0; nj < 2; ++nj)
            #pragma unroll
            for (int k = 0; k < 16; ++k)
                acc[mi][nj][k] = 0.f;

    // Zero halo columns wp==0 and wp in [57,66) for BOTH buffers.
    if (t < 160) {
        int cg   = t & 3;
        int rest = t >> 2;            // 0..39
        int row  = rest / 10;
        int zw   = rest % 10;
        int wp   = (zw == 0) ? 0 : (56 + zw);
        *(int4*)&Xs[0][xs_idx(row, wp, cg)] = make_int4(0, 0, 0, 0);
        *(int4*)&Xs[1][xs_idx(row, wp, cg)] = make_int4(0, 0, 0, 0);
    }

    // Staging map: thread -> (w = t&63, cg = t>>6); 4 rows x 8 c-strided loads.
    const int  sw     = t & 63;
    const int  sg     = t >> 6;       // cg uniform per wave -> clean b128 writes
    const bool wvalid = sw < 56;

    // Stage registers: kept as f32 so the vmcnt wait lands at the ds_write
    // AFTER compute, not at a cvt before it. 32 VGPR; total ~150 < 170 cap.
    float stg[4][8];

    auto stage_load = [&](int cc) {
        #pragma unroll
        for (int row = 0; row < 4; ++row) {
            int hin = h0 - 1 + row;
            #pragma unroll
            for (int j = 0; j < 8; ++j) stg[row][j] = 0.f;
            if (wvalid && (unsigned)hin < 56u) {
                const float* src = x + (size_t)(nb * CIN + cc * 32 + sg * 8) * NPIX
                                     + hin * HW + sw;
                #pragma unroll
                for (int j = 0; j < 8; ++j)
                    stg[row][j] = src[j * NPIX];   // coalesced across lanes
            }
        }
    };
    auto stage_write = [&](int buf) {
        if (wvalid) {
            #pragma unroll
            for (int row = 0; row < 4; ++row) {
                bf16x8 v;
                #pragma unroll
                for (int j = 0; j < 8; ++j) v[j] = (__bf16)stg[row][j];
                *(bf16x8*)&Xs[buf][xs_idx(row, 1 + sw, sg)] = v;  // ds_write_b128
            }
        }
    };

    // Prologue: fill buffer 0.
    stage_load(0);
    stage_write(0);
    __syncthreads();

    for (int cc = 0; cc < 4; ++cc) {
        // Issue next tile's global loads NOW; they complete under the MFMAs.
        if (cc < 3) stage_load(cc + 1);

        const __bf16* Xb = &Xs[cc & 1][0];
        #pragma unroll
        for (int tap = 0; tap < 9; ++tap) {
            const int r = tap / 3, s = tap % 3;
            const __bf16* wtap = W2 + (size_t)(cc * 9 + tap) * (4 * 256 * 8);
            #pragma unroll
            for (int kc = 0; kc < 2; ++kc) {
                // A-fragments: contiguous 16B/lane, W2 tap-slice is L2-resident.
                bf16x8 afr[2];
                #pragma unroll
                for (int mi = 0; mi < 2; ++mi) {
                    int oc = oc_base + mi * 32 + l31;
                    afr[mi] = *(const bf16x8*)(wtap + ((kc * 2 + half) * 256 + oc) * 8);
                }
                bf16x8 bfr[2];
                #pragma unroll
                for (int nj = 0; nj < 2; ++nj) {
                    int pw = nj * 32 + l31;
                    bfr[nj] = *(const bf16x8*)&Xb[xs_idx(prow + r, pw + s, kc * 2 + half)];
                }
                #pragma unroll
                for (int mi = 0; mi < 2; ++mi)
                    #pragma unroll
                    for (int nj = 0; nj < 2; ++nj)
                        acc[mi][nj] = __builtin_amdgcn_mfma_f32_32x32x16_bf16(
                            afr[mi], bfr[nj], acc[mi][nj], 0, 0, 0);
            }
        }

        if (cc < 3) {
            // Other buffer was last READ in compute(cc-1); the barrier at the
            // end of that iteration already fenced it. One barrier per cc.
            stage_write((cc + 1) & 1);   // vmcnt wait here: loads long done
            __syncthreads();
        }
    }

    // Epilogue: C/D 32x32 layout col=lane&31 (pos), row=(rg&3)+8*(rg>>2)+4*half (oc).
    const float bv = bias[0];
    const int hout = h0 + prow;
    #pragma unroll
    for (int nj = 0; nj < 2; ++nj) {
        int pw = nj * 32 + l31;
        if (pw < 56) {
            #pragma unroll
            for (int mi = 0; mi < 2; ++mi) {
                #pragma unroll
                for (int rg = 0; rg < 16; ++rg) {
                    int oc = oc_base + mi * 32 + (rg & 3) + ((rg >> 2) << 3) + half * 4;
                    out[(size_t)(nb * COUT + oc) * NPIX + hout * HW + pw] = acc[mi][nj][rg] + bv;
                }
            }
        }
    }
}

extern "C" void kernel_launch(void* const* d_in, const int* in_sizes, int n_in,
                              void* d_out, int out_size, void* d_ws, size_t ws_size,
                              hipStream_t stream) {
    const float* x    = (const float*)d_in[0];
    const float* Kw   = (const float*)d_in[1];
    const float* bias = (const float*)d_in[2];
    float* out = (float*)d_out;
    __bf16* W2 = (__bf16*)d_ws;   // needs 589824 bytes of workspace

    wt_transform_kernel<<<dim3(1152), dim3(256), 0, stream>>>(Kw, W2);
    conv_kernel<<<dim3(32 * 28, 2), dim3(256), 0, stream>>>(x, W2, bias, out);
}

// Round 2
// 208.777 us; speedup vs baseline: 1.1372x; 1.1372x over previous
//
#include <hip/hip_runtime.h>

typedef __bf16 bf16x8 __attribute__((ext_vector_type(8)));
typedef float  floatx16 __attribute__((ext_vector_type(16)));

#define HW   56
#define NPIX 3136
#define CIN  128
#define COUT 256

// W2 layout: [cc(4)][tap(9)][cg(4)][oc(256)][j(8)], bf16. 576 KB of d_ws.
__global__ __launch_bounds__(256) void wt_transform_kernel(
        const float* __restrict__ Kw, __bf16* __restrict__ W2) {
    int idx = blockIdx.x * 256 + threadIdx.x;     // coalesced write
    int j     = idx & 7;
    int oc    = (idx >> 3) & 255;
    int cg    = (idx >> 11) & 3;
    int tapcc = idx >> 13;                        // cc*9 + tap
    int tap   = tapcc % 9;
    int cc    = tapcc / 9;
    int c = cc * 32 + cg * 8 + j;
    W2[idx] = (__bf16)Kw[oc * 1152 + c * 9 + tap];
}

// Xs: [row(6)][wp(66)][slot(40)] bf16; slots 0..31 = ci (cg*8+j), 32..39 pad.
// Stride 40 elems = 80 B: bank-base advances 20 banks/wp -> conflict-free b128.
__device__ __forceinline__ int xs_idx(int row, int wp, int cg) {
    return row * 2640 + wp * 40 + cg * 8;
}

// R4: 512 thr = 8 waves; block tile 128 oc x 4 out-rows x 56 w. Rationale
// (R3 post-mortem): latency is hidden by cross-block TLP, not intra-wave
// pipelining — R3's async split cost VGPR/LDS occupancy and spilled. So:
// double MFMA work per barrier (8 waves/block), cut halo re-staging from
// 2x to 1.5x (6 input rows per 4 out-rows), keep per-thread regs at R2
// levels, single-buffered LDS at 31.7 KB.
__global__ __launch_bounds__(512, 3) void conv_kernel(
        const float* __restrict__ x, const __bf16* __restrict__ W2,
        const float* __restrict__ bias, float* __restrict__ out) {
    __shared__ __align__(16) __bf16 Xs[6 * 2640];   // 31.7 KB

    const int t    = threadIdx.x;
    const int nb   = blockIdx.x / 14;
    const int ht   = blockIdx.x % 14;
    const int h0   = ht * 4;
    const int ocb  = blockIdx.y * 128;

    const int wid  = t >> 6;          // 0..7
    const int lane = t & 63;
    const int half = lane >> 5;
    const int l31  = lane & 31;

    const int oc_base = ocb + (wid & 1) * 64;   // wave's 64-oc slice
    const int prow    = wid >> 1;               // wave's output row (0..3)

    floatx16 acc[2][2];
    #pragma unroll
    for (int mi = 0; mi < 2; ++mi)
        #pragma unroll
        for (int nj = 0; nj < 2; ++nj)
            #pragma unroll
            for (int k = 0; k < 16; ++k)
                acc[mi][nj][k] = 0.f;

    // Zero halo columns wp==0 and wp in [57,66): 6 rows x 10 wp x 4 cg = 240.
    if (t < 240) {
        int cg   = t & 3;
        int rest = t >> 2;            // 0..59
        int row  = rest / 10;
        int zw   = rest % 10;
        int wp   = (zw == 0) ? 0 : (56 + zw);
        *(int4*)&Xs[xs_idx(row, wp, cg)] = make_int4(0, 0, 0, 0);
    }

    // Staging map: t -> (w = t&63, cg = (t>>6)&3, rowgroup = t>>8).
    // 512 thr cover 2 rows x 4 cg x 64 w per pass; 3 passes for 6 rows.
    const int  sw     = t & 63;
    const int  sgr    = t >> 6;       // 0..7
    const int  sg     = sgr & 3;      // cg, uniform per wave -> clean b128 writes
    const int  rg2    = sgr >> 2;     // 0/1 row-group
    const bool wvalid = sw < 56;

    for (int cc = 0; cc < 4; ++cc) {
        __syncthreads();              // protect Xs against overwrite
        #pragma unroll
        for (int p = 0; p < 3; ++p) {
            int row = rg2 * 3 + p;    // rows 0..2 / 3..5
            int hin = h0 - 1 + row;
            bf16x8 v;
            #pragma unroll
            for (int j = 0; j < 8; ++j) v[j] = (__bf16)0.f;
            if (wvalid && (unsigned)hin < 56u) {
                const float* src = x + (size_t)(nb * CIN + cc * 32 + sg * 8) * NPIX
                                     + hin * HW + sw;
                #pragma unroll
                for (int j = 0; j < 8; ++j)
                    v[j] = (__bf16)src[j * NPIX];   // coalesced across lanes
            }
            if (wvalid)
                *(bf16x8*)&Xs[xs_idx(row, 1 + sw, sg)] = v;   // one ds_write_b128
        }
        __syncthreads();

        #pragma unroll
        for (int tap = 0; tap < 9; ++tap) {
            const int r = tap / 3, s = tap % 3;
            const __bf16* wtap = W2 + (size_t)(cc * 9 + tap) * (4 * 256 * 8);
            #pragma unroll
            for (int kc = 0; kc < 2; ++kc) {
                // A-fragments: contiguous 16B/lane, W2 tap-slice is L1/L2-resident
                // and shared across the 4 waves of each oc-half + resident blocks.
                bf16x8 afr[2];
                #pragma unroll
                for (int mi = 0; mi < 2; ++mi) {
                    int oc = oc_base + mi * 32 + l31;
                    afr[mi] = *(const bf16x8*)(wtap + ((kc * 2 + half) * 256 + oc) * 8);
                }
                bf16x8 bfr[2];
                #pragma unroll
                for (int nj = 0; nj < 2; ++nj) {
                    int pw = nj * 32 + l31;
                    bfr[nj] = *(const bf16x8*)&Xs[xs_idx(prow + r, pw + s, kc * 2 + half)];
                }
                #pragma unroll
                for (int mi = 0; mi < 2; ++mi)
                    #pragma unroll
                    for (int nj = 0; nj < 2; ++nj)
                        acc[mi][nj] = __builtin_amdgcn_mfma_f32_32x32x16_bf16(
                            afr[mi], bfr[nj], acc[mi][nj], 0, 0, 0);
            }
        }
    }

    // Epilogue: C/D 32x32 layout col=lane&31 (pos), row=(rg&3)+8*(rg>>2)+4*half (oc).
    const float bv = bias[0];
    const int hout = h0 + prow;
    #pragma unroll
    for (int nj = 0; nj < 2; ++nj) {
        int pw = nj * 32 + l31;
        if (pw < 56) {
            #pragma unroll
            for (int mi = 0; mi < 2; ++mi) {
                #pragma unroll
                for (int rg = 0; rg < 16; ++rg) {
                    int oc = oc_base + mi * 32 + (rg & 3) + ((rg >> 2) << 3) + half * 4;
                    out[(size_t)(nb * COUT + oc) * NPIX + hout * HW + pw] = acc[mi][nj][rg] + bv;
                }
            }
        }
    }
}

extern "C" void kernel_launch(void* const* d_in, const int* in_sizes, int n_in,
                              void* d_out, int out_size, void* d_ws, size_t ws_size,
                              hipStream_t stream) {
    const float* x    = (const float*)d_in[0];
    const float* Kw   = (const float*)d_in[1];
    const float* bias = (const float*)d_in[2];
    float* out = (float*)d_out;
    __bf16* W2 = (__bf16*)d_ws;   // needs 589824 bytes of workspace

    wt_transform_kernel<<<dim3(1152), dim3(256), 0, stream>>>(Kw, W2);
    conv_kernel<<<dim3(32 * 14, 2), dim3(512), 0, stream>>>(x, W2, bias, out);
}